// Round 5
// baseline (738.119 us; speedup 1.0000x reference)
//
#include <hip/hip_runtime.h>
#include <hip/hip_bf16.h>
#include <math.h>

// Problem constants (match reference setup_inputs)
#define N_NODES 100000
#define N_EDGES 1600000
#define F 128

// ---------------- ws layout (bytes) ----------------
// deg    : int[100000]      @ 0         (400000)
// norm   : float[100000]    @ 400000    (400000)
// offs   : int[100001]      @ 800000    (400004)
// cursor : int[100000]      @ 1200016   (400000)
// ssrc   : int[1600000]     @ 1600016   (6400000)
// bsum   : int[256]         @ 8000016   (1024)
// featn  : float[100000*128]@ 8001536   (51200000)
// wT_ih  : float[128*384]   @ 59201536  (196608)
// wT_hh  : float[128*384]   @ 59398144  (196608)
// total ≈ 59.6 MB (fallback path needs only ≈ 8 MB)

#define WS_FEATN_OFF 8001536
#define WS_WTI_OFF   59201536
#define WS_WTH_OFF   59398144
#define WS_NEED_FULL (WS_WTH_OFF + 196608)

// ---------- 1. degree count ----------
__global__ __launch_bounds__(256) void k_degree(const int* __restrict__ dst,
                                                int* __restrict__ deg) {
    int i = blockIdx.x * 256 + threadIdx.x;
    if (i < N_EDGES) atomicAdd(&deg[dst[i]], 1);
}

// ---------- 2. scan (3 kernels); scan3 also emits norm ----------
#define SCAN_B 512
#define SCAN_NB 196  // ceil(100000/512)

__global__ __launch_bounds__(SCAN_B) void k_scan1(const int* __restrict__ deg,
                                                  int* __restrict__ bsum) {
    __shared__ int s[SCAN_B];
    int t = threadIdx.x;
    int i = blockIdx.x * SCAN_B + t;
    s[t] = (i < N_NODES) ? deg[i] : 0;
    __syncthreads();
    for (int o = SCAN_B / 2; o > 0; o >>= 1) {
        if (t < o) s[t] += s[t + o];
        __syncthreads();
    }
    if (t == 0) bsum[blockIdx.x] = s[0];
}

__global__ __launch_bounds__(256) void k_scan2(int* __restrict__ bsum) {
    __shared__ int s[256];
    int t = threadIdx.x;
    int v = (t < SCAN_NB) ? bsum[t] : 0;
    s[t] = v;
    __syncthreads();
    for (int o = 1; o < 256; o <<= 1) {
        int x = (t >= o) ? s[t - o] : 0;
        __syncthreads();
        s[t] += x;
        __syncthreads();
    }
    if (t < SCAN_NB) bsum[t] = (t == 0) ? 0 : s[t - 1];  // exclusive scan of block sums
}

__global__ __launch_bounds__(SCAN_B) void k_scan3(const int* __restrict__ deg,
                                                  const int* __restrict__ bsum,
                                                  int* __restrict__ offs,
                                                  float* __restrict__ norm) {
    __shared__ int s[SCAN_B];
    int t = threadIdx.x;
    int i = blockIdx.x * SCAN_B + t;
    int v = (i < N_NODES) ? deg[i] : 0;
    s[t] = v;
    __syncthreads();
    for (int o = 1; o < SCAN_B; o <<= 1) {
        int x = (t >= o) ? s[t - o] : 0;
        __syncthreads();
        s[t] += x;
        __syncthreads();
    }
    if (i < N_NODES) {
        offs[i] = bsum[blockIdx.x] + s[t] - v;  // exclusive
        norm[i] = rsqrtf(fmaxf((float)v, 1.0f));
    }
    if (blockIdx.x == 0 && t == 0) offs[N_NODES] = N_EDGES;
}

// ---------- 3. CSR bucket fill ----------
__global__ __launch_bounds__(256) void k_fill(const int* __restrict__ src,
                                              const int* __restrict__ dst,
                                              const int* __restrict__ offs,
                                              int* __restrict__ cursor,
                                              int* __restrict__ ssrc) {
    int i = blockIdx.x * 256 + threadIdx.x;
    if (i < N_EDGES) {
        int d = dst[i];
        int p = atomicAdd(&cursor[d], 1);
        ssrc[offs[d] + p] = src[i];
    }
}

// ---------- 4. featn = feat * norm[row] (float4 elementwise) ----------
__global__ __launch_bounds__(256) void k_featn(const float* __restrict__ feat,
                                               const float* __restrict__ norm,
                                               float* __restrict__ featn) {
    int idx = blockIdx.x * 256 + threadIdx.x;  // float4 index; F/4=32 per row
    int row = idx >> 5;
    float nv = norm[row];
    float4 v = ((const float4*)feat)[idx];
    v.x *= nv; v.y *= nv; v.z *= nv; v.w *= nv;
    ((float4*)featn)[idx] = v;
}

// ---------- 5. weight transpose [384][128] -> [128][384] ----------
// so Phase C weight reads are lane-coalesced (wT[k*384 + j], consecutive j)
__global__ __launch_bounds__(256) void k_wt(const float* __restrict__ w,
                                            float* __restrict__ wT) {
    __shared__ float tile[32][33];  // +1 pad: conflict-free transpose
    int rt = blockIdx.x >> 2, ct = blockIdx.x & 3;  // 12 row-tiles x 4 col-tiles
    int r0 = rt * 32, c0 = ct * 32;
    int tr = threadIdx.x >> 5, tc = threadIdx.x & 31;  // 8 x 32
#pragma unroll
    for (int i = 0; i < 32; i += 8)
        tile[tr + i][tc] = w[(r0 + tr + i) * 128 + c0 + tc];  // coalesced read
    __syncthreads();
#pragma unroll
    for (int i = 0; i < 32; i += 8)
        wT[(c0 + tr + i) * 384 + r0 + tc] = tile[tc][tr + i];  // coalesced write
}

// ---------- 6. fused gather + rst-GEMM + GRU ----------
// PRE=true : `fsrc` = precomputed featn; `wih_`/`whh_` = TRANSPOSED weights [128][384]
// PRE=false: `fsrc` = raw feat (norm applied inline); `wih_`/`whh_` = raw [384][128]
#define ROWS 16
template <bool PRE>
__global__ __launch_bounds__(256) void k_fused(
    const float* __restrict__ fsrc, const float* __restrict__ norm,
    const int* __restrict__ offs, const int* __restrict__ ssrc,
    const float* __restrict__ W, const float* __restrict__ bias,
    const float* __restrict__ wih_, const float* __restrict__ whh_,
    const float* __restrict__ b_ih, const float* __restrict__ b_hh,
    float* __restrict__ out) {
    __shared__ float sagg[ROWS][F];
    __shared__ float sfeat[ROWS][F];
    __shared__ float srst[ROWS][F];
    __shared__ float snorm[ROWS];

    int t = threadIdx.x;
    int row0 = blockIdx.x * ROWS;

    if (t < ROWS) snorm[t] = norm[row0 + t];
    // stage featn tile for the dst rows (coalesced float4)
    for (int i = t; i < ROWS * (F / 4); i += 256) {
        int r = i >> 5, c = i & 31;
        float4 f = ((const float4*)(fsrc + (size_t)(row0 + r) * F))[c];
        if (!PRE) {
            float nv = norm[row0 + r];
            f.x *= nv; f.y *= nv; f.z *= nv; f.w *= nv;
        }
        ((float4*)&sfeat[r][0])[c] = f;
    }

    // ---- Phase A: gather-sum featn[src] rows into sagg ----
    // one wave per node (4 local nodes per wave); half-wave per edge, float4/lane;
    // 8 edges per main-loop iter -> 4 independent row-loads in flight per lane
    int wave = t >> 6, lane = t & 63;
    int hf = lane >> 5, sub = lane & 31;
    for (int ln = wave; ln < ROWS; ln += 4) {
        int node = row0 + ln;
        int beg = offs[node], end = offs[node + 1];
        float4 acc = make_float4(0.f, 0.f, 0.f, 0.f);
        int e = beg;
        for (; e + 7 < end; e += 8) {
            int s0 = ssrc[e + 0 + hf];
            int s1 = ssrc[e + 2 + hf];
            int s2 = ssrc[e + 4 + hf];
            int s3 = ssrc[e + 6 + hf];
            float4 v0 = *(const float4*)(fsrc + (size_t)s0 * F + sub * 4);
            float4 v1 = *(const float4*)(fsrc + (size_t)s1 * F + sub * 4);
            float4 v2 = *(const float4*)(fsrc + (size_t)s2 * F + sub * 4);
            float4 v3 = *(const float4*)(fsrc + (size_t)s3 * F + sub * 4);
            if (PRE) {
                acc.x += (v0.x + v1.x) + (v2.x + v3.x);
                acc.y += (v0.y + v1.y) + (v2.y + v3.y);
                acc.z += (v0.z + v1.z) + (v2.z + v3.z);
                acc.w += (v0.w + v1.w) + (v2.w + v3.w);
            } else {
                float n0 = norm[s0], n1 = norm[s1], n2 = norm[s2], n3 = norm[s3];
                acc.x = fmaf(v0.x, n0, acc.x); acc.y = fmaf(v0.y, n0, acc.y);
                acc.z = fmaf(v0.z, n0, acc.z); acc.w = fmaf(v0.w, n0, acc.w);
                acc.x = fmaf(v1.x, n1, acc.x); acc.y = fmaf(v1.y, n1, acc.y);
                acc.z = fmaf(v1.z, n1, acc.z); acc.w = fmaf(v1.w, n1, acc.w);
                acc.x = fmaf(v2.x, n2, acc.x); acc.y = fmaf(v2.y, n2, acc.y);
                acc.z = fmaf(v2.z, n2, acc.z); acc.w = fmaf(v2.w, n2, acc.w);
                acc.x = fmaf(v3.x, n3, acc.x); acc.y = fmaf(v3.y, n3, acc.y);
                acc.z = fmaf(v3.z, n3, acc.z); acc.w = fmaf(v3.w, n3, acc.w);
            }
        }
        for (; e < end; e += 2) {  // remainder 0..7 edges (odd handled by guard)
            int edge = e + hf;
            if (edge < end) {
                int s0 = ssrc[edge];
                float4 v0 = *(const float4*)(fsrc + (size_t)s0 * F + sub * 4);
                float n0 = PRE ? 1.0f : norm[s0];
                acc.x = fmaf(v0.x, n0, acc.x); acc.y = fmaf(v0.y, n0, acc.y);
                acc.z = fmaf(v0.z, n0, acc.z); acc.w = fmaf(v0.w, n0, acc.w);
            }
        }
        // combine the two half-wave partial sums
        acc.x += __shfl_xor(acc.x, 32, 64);
        acc.y += __shfl_xor(acc.y, 32, 64);
        acc.z += __shfl_xor(acc.z, 32, 64);
        acc.w += __shfl_xor(acc.w, 32, 64);
        if (hf == 0) *(float4*)&sagg[ln][sub * 4] = acc;
    }
    __syncthreads();

    // ---- Phase B: srst = (sagg @ W) * norm + bias ----
    int j = t & 127;
    int rg = (t >> 7) * 8;  // 0 or 8
    {
        float acc[8] = {0, 0, 0, 0, 0, 0, 0, 0};
        for (int k = 0; k < F; k += 4) {
            float w0 = W[(k + 0) * F + j];  // coalesced across lanes
            float w1 = W[(k + 1) * F + j];
            float w2 = W[(k + 2) * F + j];
            float w3 = W[(k + 3) * F + j];
#pragma unroll
            for (int r = 0; r < 8; ++r) {
                float4 a = *(const float4*)&sagg[rg + r][k];  // LDS broadcast
                acc[r] = fmaf(a.x, w0, acc[r]);
                acc[r] = fmaf(a.y, w1, acc[r]);
                acc[r] = fmaf(a.z, w2, acc[r]);
                acc[r] = fmaf(a.w, w3, acc[r]);
            }
        }
        float bj = bias[j];
#pragma unroll
        for (int r = 0; r < 8; ++r) {
            srst[rg + r][j] = acc[r] * snorm[rg + r] + bj;
        }
    }
    __syncthreads();

    // ---- Phase C: GRU gates (gi from sfeat, gh from srst) ----
    float air[8] = {0}, aiz[8] = {0}, ain[8] = {0};
    float ahr[8] = {0}, ahz[8] = {0}, ahn[8] = {0};

    if (PRE) {
        // transposed weights: wT[k*384 + (gate*128 + j)] — lane-coalesced
        for (int k = 0; k < F; k += 4) {
            float wi[3][4], wh[3][4];
#pragma unroll
            for (int kk = 0; kk < 4; ++kk) {
                const float* wik = wih_ + (size_t)(k + kk) * 384 + j;
                const float* whk = whh_ + (size_t)(k + kk) * 384 + j;
                wi[0][kk] = wik[0];   wi[1][kk] = wik[128]; wi[2][kk] = wik[256];
                wh[0][kk] = whk[0];   wh[1][kk] = whk[128]; wh[2][kk] = whk[256];
            }
#pragma unroll
            for (int r = 0; r < 8; ++r) {
                float4 a = *(const float4*)&sfeat[rg + r][k];  // LDS broadcast
                float4 h = *(const float4*)&srst[rg + r][k];
                air[r] = fmaf(a.x, wi[0][0], air[r]); air[r] = fmaf(a.y, wi[0][1], air[r]);
                air[r] = fmaf(a.z, wi[0][2], air[r]); air[r] = fmaf(a.w, wi[0][3], air[r]);
                aiz[r] = fmaf(a.x, wi[1][0], aiz[r]); aiz[r] = fmaf(a.y, wi[1][1], aiz[r]);
                aiz[r] = fmaf(a.z, wi[1][2], aiz[r]); aiz[r] = fmaf(a.w, wi[1][3], aiz[r]);
                ain[r] = fmaf(a.x, wi[2][0], ain[r]); ain[r] = fmaf(a.y, wi[2][1], ain[r]);
                ain[r] = fmaf(a.z, wi[2][2], ain[r]); ain[r] = fmaf(a.w, wi[2][3], ain[r]);
                ahr[r] = fmaf(h.x, wh[0][0], ahr[r]); ahr[r] = fmaf(h.y, wh[0][1], ahr[r]);
                ahr[r] = fmaf(h.z, wh[0][2], ahr[r]); ahr[r] = fmaf(h.w, wh[0][3], ahr[r]);
                ahz[r] = fmaf(h.x, wh[1][0], ahz[r]); ahz[r] = fmaf(h.y, wh[1][1], ahz[r]);
                ahz[r] = fmaf(h.z, wh[1][2], ahz[r]); ahz[r] = fmaf(h.w, wh[1][3], ahz[r]);
                ahn[r] = fmaf(h.x, wh[2][0], ahn[r]); ahn[r] = fmaf(h.y, wh[2][1], ahn[r]);
                ahn[r] = fmaf(h.z, wh[2][2], ahn[r]); ahn[r] = fmaf(h.w, wh[2][3], ahn[r]);
            }
        }
    } else {
        // fallback: raw [384][128] row-major weight rows (uncoalesced but correct)
        const float* wir = wih_ + (size_t)(j + 0) * F;
        const float* wiz = wih_ + (size_t)(j + 128) * F;
        const float* win = wih_ + (size_t)(j + 256) * F;
        const float* whr = whh_ + (size_t)(j + 0) * F;
        const float* whz = whh_ + (size_t)(j + 128) * F;
        const float* whn = whh_ + (size_t)(j + 256) * F;
        for (int k = 0; k < F; k += 4) {
            float4 bir = *(const float4*)(wir + k);
            float4 biz = *(const float4*)(wiz + k);
            float4 bin = *(const float4*)(win + k);
            float4 bhr = *(const float4*)(whr + k);
            float4 bhz = *(const float4*)(whz + k);
            float4 bhn = *(const float4*)(whn + k);
#pragma unroll
            for (int r = 0; r < 8; ++r) {
                float4 a = *(const float4*)&sfeat[rg + r][k];
                float4 h = *(const float4*)&srst[rg + r][k];
                air[r] = fmaf(a.x, bir.x, air[r]); air[r] = fmaf(a.y, bir.y, air[r]);
                air[r] = fmaf(a.z, bir.z, air[r]); air[r] = fmaf(a.w, bir.w, air[r]);
                aiz[r] = fmaf(a.x, biz.x, aiz[r]); aiz[r] = fmaf(a.y, biz.y, aiz[r]);
                aiz[r] = fmaf(a.z, biz.z, aiz[r]); aiz[r] = fmaf(a.w, biz.w, aiz[r]);
                ain[r] = fmaf(a.x, bin.x, ain[r]); ain[r] = fmaf(a.y, bin.y, ain[r]);
                ain[r] = fmaf(a.z, bin.z, ain[r]); ain[r] = fmaf(a.w, bin.w, ain[r]);
                ahr[r] = fmaf(h.x, bhr.x, ahr[r]); ahr[r] = fmaf(h.y, bhr.y, ahr[r]);
                ahr[r] = fmaf(h.z, bhr.z, ahr[r]); ahr[r] = fmaf(h.w, bhr.w, ahr[r]);
                ahz[r] = fmaf(h.x, bhz.x, ahz[r]); ahz[r] = fmaf(h.y, bhz.y, ahz[r]);
                ahz[r] = fmaf(h.z, bhz.z, ahz[r]); ahz[r] = fmaf(h.w, bhz.w, ahz[r]);
                ahn[r] = fmaf(h.x, bhn.x, ahn[r]); ahn[r] = fmaf(h.y, bhn.y, ahn[r]);
                ahn[r] = fmaf(h.z, bhn.z, ahn[r]); ahn[r] = fmaf(h.w, bhn.w, ahn[r]);
            }
        }
    }

    float Bir = b_ih[j], Biz = b_ih[j + 128], Bin = b_ih[j + 256];
    float Bhr = b_hh[j], Bhz = b_hh[j + 128], Bhn = b_hh[j + 256];
#pragma unroll
    for (int r = 0; r < 8; ++r) {
        int row = row0 + rg + r;
        float ir = air[r] + Bir, hr = ahr[r] + Bhr;
        float iz = aiz[r] + Biz, hz = ahz[r] + Bhz;
        float in_ = ain[r] + Bin, hn = ahn[r] + Bhn;
        float rr = 1.0f / (1.0f + __expf(-(ir + hr)));
        float zz = 1.0f / (1.0f + __expf(-(iz + hz)));
        float nn = tanhf(in_ + rr * hn);
        float rstv = srst[rg + r][j];
        out[(size_t)row * F + j] = (1.0f - zz) * nn + zz * rstv;
    }
}

extern "C" void kernel_launch(void* const* d_in, const int* in_sizes, int n_in,
                              void* d_out, int out_size, void* d_ws, size_t ws_size,
                              hipStream_t stream) {
    const float* feat   = (const float*)d_in[0];
    const float* weight = (const float*)d_in[1];
    const float* bias   = (const float*)d_in[2];
    const float* w_ih   = (const float*)d_in[3];
    const float* w_hh   = (const float*)d_in[4];
    const float* b_ih   = (const float*)d_in[5];
    const float* b_hh   = (const float*)d_in[6];
    const int*   src    = (const int*)d_in[7];
    const int*   dst    = (const int*)d_in[8];
    float* out = (float*)d_out;

    char* ws = (char*)d_ws;
    int*   deg    = (int*)(ws + 0);
    float* norm   = (float*)(ws + 400000);
    int*   offs   = (int*)(ws + 800000);
    int*   cursor = (int*)(ws + 1200016);
    int*   ssrc   = (int*)(ws + 1600016);
    int*   bsum   = (int*)(ws + 8000016);
    float* featn  = (float*)(ws + WS_FEATN_OFF);
    float* wT_ih  = (float*)(ws + WS_WTI_OFF);
    float* wT_hh  = (float*)(ws + WS_WTH_OFF);

    hipMemsetAsync(deg, 0, N_NODES * sizeof(int), stream);
    hipMemsetAsync(cursor, 0, N_NODES * sizeof(int), stream);

    k_degree<<<(N_EDGES + 255) / 256, 256, 0, stream>>>(dst, deg);
    k_scan1<<<SCAN_NB, SCAN_B, 0, stream>>>(deg, bsum);
    k_scan2<<<1, 256, 0, stream>>>(bsum);
    k_scan3<<<SCAN_NB, SCAN_B, 0, stream>>>(deg, bsum, offs, norm);
    k_fill<<<(N_EDGES + 255) / 256, 256, 0, stream>>>(src, dst, offs, cursor, ssrc);

    if (ws_size >= WS_NEED_FULL) {
        k_wt<<<48, 256, 0, stream>>>(w_ih, wT_ih);
        k_wt<<<48, 256, 0, stream>>>(w_hh, wT_hh);
        k_featn<<<(N_NODES * F / 4) / 256, 256, 0, stream>>>(feat, norm, featn);
        k_fused<true><<<N_NODES / ROWS, 256, 0, stream>>>(featn, norm, offs, ssrc,
                                                          weight, bias, wT_ih, wT_hh,
                                                          b_ih, b_hh, out);
    } else {
        k_fused<false><<<N_NODES / ROWS, 256, 0, stream>>>(feat, norm, offs, ssrc,
                                                           weight, bias, w_ih, w_hh,
                                                           b_ih, b_hh, out);
    }
}